// Round 11
// baseline (259.368 us; speedup 1.0000x reference)
//
#include <hip/hip_runtime.h>
#include <hip/hip_cooperative_groups.h>
#include <math.h>

namespace cg = cooperative_groups;

#define HW    65536
#define OC    128      // quantum channels
#define C2    256      // 2*OUT_C bn channels
#define NANS  2
#define EPS_  1e-5f

struct cplx { float re, im; };
__device__ __forceinline__ cplx cmul(cplx a, cplx b){ return {a.re*b.re - a.im*b.im, a.re*b.im + a.im*b.re}; }
__device__ __forceinline__ cplx cadd(cplx a, cplx b){ return {a.re+b.re, a.im+b.im}; }
__device__ __forceinline__ cplx cconj(cplx a){ return {a.re, -a.im}; }

__constant__ constexpr int TM4[4] = {-1, 0, 0, 1};
__constant__ constexpr int TN4[4] = { 0,-1, 1, 0};
__constant__ constexpr int SIDX25[25] = {
    -1,-1, 0,-1,-1,
    -1, 1,-1, 2,-1,
     3,-1, 4,-1, 5,
    -1, 6,-1, 7,-1,
    -1,-1, 8,-1,-1 };
__constant__ constexpr int SM9[9] = {-2,-1,-1, 0, 0, 0, 1, 1, 2};
__constant__ constexpr int SN9[9] = { 0,-1, 1,-2, 0, 2,-1, 1, 0};
__constant__ constexpr int FM13[13] = {0, 1, 1, 2, 0, 2, 2, 4, 0, 3, 3, 1, 1};
__constant__ constexpr int FN13[13] = {0, 1,-1, 0, 2, 2,-2, 0, 4, 1,-1, 3,-3};

// ---------------- circuit helpers ----------------
__device__ __forceinline__ void make_u3(const float* __restrict__ p, cplx U[2][2]) {
    float th = p[0], ph = p[1], lm = p[2];
    float ct = cosf(th * 0.5f), st = sinf(th * 0.5f);
    float cl = cosf(lm), sl = sinf(lm);
    float cp = cosf(ph), sp = sinf(ph);
    float cpl = cosf(ph + lm), spl = sinf(ph + lm);
    U[0][0] = {ct, 0.f};
    U[0][1] = {-cl * st, -sl * st};
    U[1][0] = {cp * st, sp * st};
    U[1][1] = {cpl * ct, spl * ct};
}
__device__ __forceinline__ void apply_u3_w0(cplx v[4], const cplx U[2][2]) {
    cplx a0 = cadd(cmul(U[0][0], v[0]), cmul(U[0][1], v[2]));
    cplx a1 = cadd(cmul(U[0][0], v[1]), cmul(U[0][1], v[3]));
    cplx a2 = cadd(cmul(U[1][0], v[0]), cmul(U[1][1], v[2]));
    cplx a3 = cadd(cmul(U[1][0], v[1]), cmul(U[1][1], v[3]));
    v[0]=a0; v[1]=a1; v[2]=a2; v[3]=a3;
}
__device__ __forceinline__ void apply_u3_w1(cplx v[4], const cplx U[2][2]) {
    cplx a0 = cadd(cmul(U[0][0], v[0]), cmul(U[0][1], v[1]));
    cplx a1 = cadd(cmul(U[1][0], v[0]), cmul(U[1][1], v[1]));
    cplx a2 = cadd(cmul(U[0][0], v[2]), cmul(U[0][1], v[3]));
    cplx a3 = cadd(cmul(U[1][0], v[2]), cmul(U[1][1], v[3]));
    v[0]=a0; v[1]=a1; v[2]=a2; v[3]=a3;
}
__device__ __forceinline__ void apply_level(cplx v[4], const float* __restrict__ qp, int lvl, int o) {
    #pragma unroll
    for (int j = 0; j < NANS; j++) {
        cplx U0[2][2], U1[2][2];
        make_u3(qp + (((lvl * NANS + j) * C2) + 2 * o    ) * 3, U0);
        make_u3(qp + (((lvl * NANS + j) * C2) + 2 * o + 1) * 3, U1);
        apply_u3_w0(v, U0);
        apply_u3_w1(v, U1);
        cplx t = v[2]; v[2] = v[3]; v[3] = t;   // CNOT
    }
}

// ---------------- shared coeff-phase body (used by coop phase 2 and fallback B) ----------------
// s[5] = stats totals (valid on lanes 0..63 at least); writes ws_ch[o*32 .. +31].
__device__ __forceinline__ void coeff_block_body(int o, int t, const float s[5],
                                                 const float* __restrict__ F,
                                                 const float* __restrict__ qparam,
                                                 const float* __restrict__ g,
                                                 const float* __restrict__ bb,
                                                 float* __restrict__ ws_ch,
                                                 cplx (*cols)[4], float (*pq)[25]) {
    if (t < 9) {
        int lvl  = (t < 4) ? 1 : ((t < 8) ? 2 : 0);
        int kidx = (t < 4) ? t : ((t < 8) ? t - 4 : 0);
        cplx v[4] = {{0,0},{0,0},{0,0},{0,0}};
        v[kidx] = {1.f, 0.f};
        apply_level(v, qparam, lvl, o);
        #pragma unroll
        for (int r = 0; r < 4; r++) cols[t][r] = v[r];
    }
    __syncthreads();
    if (t < 4) {
        int r = t;
        cplx psi0c[4];
        #pragma unroll
        for (int l = 0; l < 4; l++) psi0c[l] = cols[8][l];
        cplx B1[4][4];
        #pragma unroll
        for (int l = 0; l < 4; l++)
            #pragma unroll
            for (int k = 0; k < 4; k++) B1[k][l] = cmul(cols[l][k], psi0c[l]);
        cplx A2r[4];
        #pragma unroll
        for (int k = 0; k < 4; k++) A2r[k] = cols[4 + k][r];

        cplx W[9];
        #pragma unroll
        for (int q = 0; q < 9; q++) W[q] = {0.f, 0.f};
        #pragma unroll
        for (int k = 0; k < 4; k++)
            #pragma unroll
            for (int l = 0; l < 4; l++) {
                cplx G = cmul(A2r[k], B1[k][l]);
                int si = SIDX25[(TM4[k] + TM4[l] + 2) * 5 + (TN4[k] + TN4[l] + 2)];
                W[si] = cadd(W[si], G);
            }
        cplx Acc[9][9];
        #pragma unroll
        for (int i = 0; i < 9; i++)
            #pragma unroll
            for (int j = 0; j < 9; j++) Acc[i][j] = {0.f, 0.f};
        #pragma unroll
        for (int s1 = 0; s1 < 9; s1++)
            #pragma unroll
            for (int s2 = 0; s2 < 9; s2++) {
                int mi = SM9[s1] - SM9[s2] + 4;
                int ni = SN9[s1] - SN9[s2] + 4;
                cplx X = cmul(W[s1], cconj(W[s2]));
                Acc[mi][ni] = cadd(Acc[mi][ni], X);
            }
        float sr = (r < 2) ? 1.f : -1.f;
        pq[r][0] = sr * Acc[4][4].re;
        #pragma unroll
        for (int f = 1; f < 13; f++) {
            cplx e1 = Acc[FM13[f] + 4][FN13[f] + 4];
            cplx e2 = Acc[4 - FM13[f]][4 - FN13[f]];
            pq[r][2 * f - 1] = sr * (e1.re + e2.re);
            pq[r][2 * f]     = -sr * (e1.im - e2.im);
        }
    }
    if (t < 2) {
        int c = 2 * o + t;
        const float Ninv = 1.0f / 65536.0f;
        float m0 = s[0] * Ninv, m1 = s[1] * Ninv;
        float F0 = F[c * 2 + 0], F1 = F[c * 2 + 1];
        float mean = F0 * m0 + F1 * m1;
        float ex2  = (F0 * F0 * s[2] + 2.f * F0 * F1 * s[4] + F1 * F1 * s[3]) * Ninv;
        float var  = ex2 - mean * mean;
        float scale = g[c] / sqrtf(var + EPS_);
        float* dst = ws_ch + o * 32 + t * 3;
        dst[0] = F0 * scale;
        dst[1] = F1 * scale;
        dst[2] = bb[c] - mean * scale;
    }
    __syncthreads();
    if (t == 0) {
        float* co = ws_ch + o * 32;
        #pragma unroll
        for (int j = 0; j < 25; j++)
            co[6 + j] = pq[0][j] + pq[1][j] + pq[2][j] + pq[3][j];
    }
}

// ---------------- per-pixel evaluation (Fourier form) ----------------
__device__ __forceinline__ float qf_ev(float c0, float c1, const float* __restrict__ C) {
    float x0 = fmaf(C[0], c0, fmaf(C[1], c1, C[2]));
    float x1 = fmaf(C[3], c0, fmaf(C[4], c1, C[5]));
    float a = 0.5f * (x0 + x1), b = 0.5f * (x0 - x1);
    float sa, ca, sb, cb;
    __sincosf(a, &sa, &ca);
    __sincosf(b, &sb, &cb);
    float cc = ca * cb, ss = sa * sb, sc = sa * cb, cs = ca * sb;
    float c11  = cc - ss,  s11  = sc + cs;
    float c1m1 = cc + ss,  s1m1 = sc - cs;
    float c20 = fmaf(ca, ca, -sa * sa), s20 = 2.f * sa * ca;
    float c02 = fmaf(cb, cb, -sb * sb), s02 = 2.f * sb * cb;
    float pa = c20 * c02, pb = s20 * s02, pc = s20 * c02, pd = c20 * s02;
    float c22  = pa - pb, s22  = pc + pd;
    float c2m2 = pa + pb, s2m2 = pc - pd;
    float c40 = fmaf(c20, c20, -s20 * s20), s40 = 2.f * s20 * c20;
    float c04 = fmaf(c02, c02, -s02 * s02), s04 = 2.f * s02 * c02;
    float c31  = fmaf(c20, c11, -s20 * s11),  s31  = fmaf(s20, c11,  c20 * s11);
    float c3m1 = fmaf(c20, c1m1, -s20 * s1m1), s3m1 = fmaf(s20, c1m1, c20 * s1m1);
    float c13  = fmaf(c02, c11, -s02 * s11),  s13  = fmaf(s02, c11,  c02 * s11);
    float c1m3 = fmaf(c1m1, c02, s1m1 * s02), s1m3 = fmaf(s1m1, c02, -c1m1 * s02);
    float ev = C[6];
    ev = fmaf(C[7],  c11,  ev); ev = fmaf(C[8],  s11,  ev);
    ev = fmaf(C[9],  c1m1, ev); ev = fmaf(C[10], s1m1, ev);
    ev = fmaf(C[11], c20,  ev); ev = fmaf(C[12], s20,  ev);
    ev = fmaf(C[13], c02,  ev); ev = fmaf(C[14], s02,  ev);
    ev = fmaf(C[15], c22,  ev); ev = fmaf(C[16], s22,  ev);
    ev = fmaf(C[17], c2m2, ev); ev = fmaf(C[18], s2m2, ev);
    ev = fmaf(C[19], c40,  ev); ev = fmaf(C[20], s40,  ev);
    ev = fmaf(C[21], c04,  ev); ev = fmaf(C[22], s04,  ev);
    ev = fmaf(C[23], c31,  ev); ev = fmaf(C[24], s31,  ev);
    ev = fmaf(C[25], c3m1, ev); ev = fmaf(C[26], s3m1, ev);
    ev = fmaf(C[27], c13,  ev); ev = fmaf(C[28], s13,  ev);
    ev = fmaf(C[29], c1m3, ev); ev = fmaf(C[30], s1m3, ev);
    return ev;
}

// ================= Cooperative single kernel =================
// grid = 1024 blocks x 256 threads, launch_bounds(256,4) -> 4 blocks/CU co-resident.
__global__ __launch_bounds__(256, 4) void qf_all(const float4* __restrict__ coords4,
                                                 const float* __restrict__ F,
                                                 const float* __restrict__ qparam,
                                                 const float* __restrict__ g,
                                                 const float* __restrict__ bb,
                                                 float* __restrict__ part,
                                                 float* __restrict__ ws_ch,
                                                 float4* __restrict__ out4) {
    cg::grid_group grid = cg::this_grid();
    int bid = blockIdx.x, t = threadIdx.x;

    __shared__ float sm[4][5];
    __shared__ cplx cols[9][4];
    __shared__ float pq[4][25];

    // ---- phase 1: stats partials (blocks 0..63, one float4-pair per thread) ----
    if (bid < 64) {
        int i = bid * 256 + t;                 // 0..16383
        float4 a = coords4[i];
        float4 b = coords4[16384 + i];
        float v[5];
        v[0] = (a.x + a.y) + (a.z + a.w);
        v[1] = (b.x + b.y) + (b.z + b.w);
        v[2] = fmaf(a.x, a.x, a.y * a.y) + fmaf(a.z, a.z, a.w * a.w);
        v[3] = fmaf(b.x, b.x, b.y * b.y) + fmaf(b.z, b.z, b.w * b.w);
        v[4] = fmaf(a.x, b.x, a.y * b.y) + fmaf(a.z, b.z, a.w * b.w);
        #pragma unroll
        for (int k = 0; k < 5; k++) {
            #pragma unroll
            for (int off = 32; off; off >>= 1) v[k] += __shfl_xor(v[k], off, 64);
        }
        int lane = t & 63, wid = t >> 6;
        if (lane == 0) {
            #pragma unroll
            for (int k = 0; k < 5; k++) sm[wid][k] = v[k];
        }
        __syncthreads();
        if (t == 0) {
            #pragma unroll
            for (int k = 0; k < 5; k++)
                part[bid * 5 + k] = sm[0][k] + sm[1][k] + sm[2][k] + sm[3][k];
        }
    }
    grid.sync();

    // ---- phase 2: per-channel coeffs (blocks 0..127, one per channel) ----
    if (bid < OC) {
        float s[5] = {0,0,0,0,0};
        if (t < 64) {
            #pragma unroll
            for (int k = 0; k < 5; k++) s[k] = part[t * 5 + k];
            #pragma unroll
            for (int k = 0; k < 5; k++) {
                #pragma unroll
                for (int off = 32; off; off >>= 1) s[k] += __shfl_xor(s[k], off, 64);
            }
        }
        coeff_block_body(bid, t, s, F, qparam, g, bb, ws_ch, cols, pq);
    }
    grid.sync();

    // ---- phase 3: pixel evaluation; 8 blocks per channel, 8 groups per thread ----
    int o = bid >> 3, sub = bid & 7;
    const float* __restrict__ co = ws_ch + o * 32;
    float Creg[31];
    #pragma unroll
    for (int j = 0; j < 31; j++) Creg[j] = co[j];
    const size_t plane4 = (size_t)OC * (HW / 4);
    size_t obase = (size_t)o * (HW / 4);
    #pragma unroll
    for (int j = 0; j < 8; j++) {
        int p4 = sub * 2048 + j * 256 + t;
        float4 c0v = coords4[p4];
        float4 c1v = coords4[16384 + p4];
        float4 r;
        r.x = qf_ev(c0v.x, c1v.x, Creg);
        r.y = qf_ev(c0v.y, c1v.y, Creg);
        r.z = qf_ev(c0v.z, c1v.z, Creg);
        r.w = qf_ev(c0v.w, c1v.w, Creg);
        size_t basei = obase + (size_t)p4;
        out4[basei] = r;
        out4[basei + plane4] = r;
        out4[basei + 2 * plane4] = r;
        out4[basei + 3 * plane4] = r;
    }
}

// ================= Fallback: proven r4 3-kernel chain =================
__global__ __launch_bounds__(256) void qf_stats_partial(const float* __restrict__ coords,
                                                        float* __restrict__ part) {
    int i = blockIdx.x * 256 + threadIdx.x;
    float c0 = coords[i];
    float c1 = coords[HW + i];
    float v[5] = {c0, c1, c0*c0, c1*c1, c0*c1};
    #pragma unroll
    for (int k = 0; k < 5; k++) {
        float x = v[k];
        #pragma unroll
        for (int off = 32; off; off >>= 1) x += __shfl_down(x, off, 64);
        v[k] = x;
    }
    __shared__ float sm[4][5];
    int lane = threadIdx.x & 63, wid = threadIdx.x >> 6;
    if (lane == 0) {
        #pragma unroll
        for (int k = 0; k < 5; k++) sm[wid][k] = v[k];
    }
    __syncthreads();
    if (threadIdx.x == 0) {
        #pragma unroll
        for (int k = 0; k < 5; k++)
            part[blockIdx.x * 5 + k] = sm[0][k] + sm[1][k] + sm[2][k] + sm[3][k];
    }
}

__global__ __launch_bounds__(64) void qf_coeffs(const float* __restrict__ part,
                                                const float* __restrict__ F,
                                                const float* __restrict__ qparam,
                                                const float* __restrict__ g,
                                                const float* __restrict__ bb,
                                                float* __restrict__ ws_ch) {
    int o = blockIdx.x;
    int lane = threadIdx.x;
    float s[5] = {0,0,0,0,0};
    for (int b = lane; b < 256; b += 64) {
        #pragma unroll
        for (int k = 0; k < 5; k++) s[k] += part[b * 5 + k];
    }
    #pragma unroll
    for (int k = 0; k < 5; k++) {
        #pragma unroll
        for (int off = 32; off; off >>= 1) s[k] += __shfl_xor(s[k], off, 64);
    }
    __shared__ cplx cols[9][4];
    __shared__ float pq[4][25];
    coeff_block_body(o, lane, s, F, qparam, g, bb, ws_ch, cols, pq);
}

__global__ __launch_bounds__(256) void qf_main(const float4* __restrict__ coords4,
                                               const float* __restrict__ ch,
                                               float4* __restrict__ out4) {
    int p4 = blockIdx.x * 256 + threadIdx.x;
    int o = blockIdx.y;
    const float* __restrict__ C = ch + o * 32;
    float4 c0v = coords4[p4];
    float4 c1v = coords4[(HW / 4) + p4];
    float4 r;
    r.x = qf_ev(c0v.x, c1v.x, C);
    r.y = qf_ev(c0v.y, c1v.y, C);
    r.z = qf_ev(c0v.z, c1v.z, C);
    r.w = qf_ev(c0v.w, c1v.w, C);
    size_t base = (size_t)o * (HW / 4) + (size_t)p4;
    const size_t plane4 = (size_t)OC * (HW / 4);
    out4[base] = r;
    out4[base + plane4] = r;
    out4[base + 2 * plane4] = r;
    out4[base + 3 * plane4] = r;
}

extern "C" void kernel_launch(void* const* d_in, const int* in_sizes, int n_in,
                              void* d_out, int out_size, void* d_ws, size_t ws_size,
                              hipStream_t stream) {
    const float* coords = (const float*)d_in[0];
    const float* F      = (const float*)d_in[1];
    const float* qparam = (const float*)d_in[2];
    const float* g      = (const float*)d_in[3];
    const float* bb     = (const float*)d_in[4];
    float* out = (float*)d_out;

    float* ws    = (float*)d_ws;
    float* part  = ws;              // coop: 64*5 ; fallback: 256*5 (fits in 2048)
    float* ws_ch = ws + 2048;       // 128*32 floats

    const float4* coords4 = (const float4*)coords;
    float4* out4 = (float4*)out;

    void* args[] = { (void*)&coords4, (void*)&F, (void*)&qparam, (void*)&g,
                     (void*)&bb, (void*)&part, (void*)&ws_ch, (void*)&out4 };
    hipError_t err = hipLaunchCooperativeKernel((const void*)qf_all,
                                                dim3(1024), dim3(256),
                                                args, 0, stream);
    if (err != hipSuccess) {
        // deterministic fallback: proven 3-kernel chain (round-4 structure)
        qf_stats_partial<<<dim3(256), dim3(256), 0, stream>>>(coords, part);
        qf_coeffs<<<dim3(OC), dim3(64), 0, stream>>>(part, F, qparam, g, bb, ws_ch);
        qf_main<<<dim3(HW / 4 / 256, OC), dim3(256), 0, stream>>>(coords4, ws_ch, out4);
    }
}

// Round 12
// 49.743 us; speedup vs baseline: 5.2142x; 5.2142x over previous
//
#include <hip/hip_runtime.h>
#include <math.h>

#define HW    65536
#define OC    128      // quantum channels
#define C2    256      // 2*OUT_C bn channels
#define NANS  2
#define EPS_  1e-5f

struct cplx { float re, im; };
__device__ __forceinline__ cplx cmul(cplx a, cplx b){ return {a.re*b.re - a.im*b.im, a.re*b.im + a.im*b.re}; }
__device__ __forceinline__ cplx cadd(cplx a, cplx b){ return {a.re+b.re, a.im+b.im}; }
__device__ __forceinline__ cplx cconj(cplx a){ return {a.re, -a.im}; }

// compile-time tables (file-scope constexpr so unrolled indexing folds)
__constant__ constexpr int TM4[4] = {-1, 0, 0, 1};
__constant__ constexpr int TN4[4] = { 0,-1, 1, 0};
// star points s = t_k + t_l: 0:(-2,0) 1:(-1,-1) 2:(-1,1) 3:(0,-2) 4:(0,0) 5:(0,2) 6:(1,-1) 7:(1,1) 8:(2,0)
__constant__ constexpr int SIDX25[25] = {
    -1,-1, 0,-1,-1,
    -1, 1,-1, 2,-1,
     3,-1, 4,-1, 5,
    -1, 6,-1, 7,-1,
    -1,-1, 8,-1,-1 };
__constant__ constexpr int SM9[9] = {-2,-1,-1, 0, 0, 0, 1, 1, 2};
__constant__ constexpr int SN9[9] = { 0,-1, 1,-2, 0, 2,-1, 1, 0};
__constant__ constexpr int FM13[13] = {0, 1, 1, 2, 0, 2, 2, 4, 0, 3, 3, 1, 1};
__constant__ constexpr int FN13[13] = {0, 1,-1, 0, 2, 2,-2, 0, 4, 1,-1, 3,-3};

// ---------------- Kernel A: partial stats over c0, c1 (sample 0) ----------------
__global__ __launch_bounds__(256) void qf_stats_partial(const float* __restrict__ coords,
                                                        float* __restrict__ part) {
    int i = blockIdx.x * 256 + threadIdx.x;
    float c0 = coords[i];
    float c1 = coords[HW + i];
    float v[5] = {c0, c1, c0*c0, c1*c1, c0*c1};
    #pragma unroll
    for (int k = 0; k < 5; k++) {
        float x = v[k];
        #pragma unroll
        for (int off = 32; off; off >>= 1) x += __shfl_down(x, off, 64);
        v[k] = x;
    }
    __shared__ float sm[4][5];
    int lane = threadIdx.x & 63, wid = threadIdx.x >> 6;
    if (lane == 0) {
        #pragma unroll
        for (int k = 0; k < 5; k++) sm[wid][k] = v[k];
    }
    __syncthreads();
    if (threadIdx.x == 0) {
        #pragma unroll
        for (int k = 0; k < 5; k++)
            part[blockIdx.x * 5 + k] = sm[0][k] + sm[1][k] + sm[2][k] + sm[3][k];
    }
}

// ---------------- circuit helpers (precompute only) ----------------
__device__ __forceinline__ void make_u3(const float* __restrict__ p, cplx U[2][2]) {
    float th = p[0], ph = p[1], lm = p[2];
    float ct = cosf(th * 0.5f), st = sinf(th * 0.5f);
    float cl = cosf(lm), sl = sinf(lm);
    float cp = cosf(ph), sp = sinf(ph);
    float cpl = cosf(ph + lm), spl = sinf(ph + lm);
    U[0][0] = {ct, 0.f};
    U[0][1] = {-cl * st, -sl * st};
    U[1][0] = {cp * st, sp * st};
    U[1][1] = {cpl * ct, spl * ct};
}
__device__ __forceinline__ void apply_u3_w0(cplx v[4], const cplx U[2][2]) {
    cplx a0 = cadd(cmul(U[0][0], v[0]), cmul(U[0][1], v[2]));
    cplx a1 = cadd(cmul(U[0][0], v[1]), cmul(U[0][1], v[3]));
    cplx a2 = cadd(cmul(U[1][0], v[0]), cmul(U[1][1], v[2]));
    cplx a3 = cadd(cmul(U[1][0], v[1]), cmul(U[1][1], v[3]));
    v[0]=a0; v[1]=a1; v[2]=a2; v[3]=a3;
}
__device__ __forceinline__ void apply_u3_w1(cplx v[4], const cplx U[2][2]) {
    cplx a0 = cadd(cmul(U[0][0], v[0]), cmul(U[0][1], v[1]));
    cplx a1 = cadd(cmul(U[1][0], v[0]), cmul(U[1][1], v[1]));
    cplx a2 = cadd(cmul(U[0][0], v[2]), cmul(U[0][1], v[3]));
    cplx a3 = cadd(cmul(U[1][0], v[2]), cmul(U[1][1], v[3]));
    v[0]=a0; v[1]=a1; v[2]=a2; v[3]=a3;
}
__device__ __forceinline__ void apply_level(cplx v[4], const float* __restrict__ qp, int lvl, int o) {
    #pragma unroll
    for (int j = 0; j < NANS; j++) {
        cplx U0[2][2], U1[2][2];
        make_u3(qp + (((lvl * NANS + j) * C2) + 2 * o    ) * 3, U0);
        make_u3(qp + (((lvl * NANS + j) * C2) + 2 * o + 1) * 3, U1);
        apply_u3_w0(v, U0);
        apply_u3_w1(v, U1);
        cplx t = v[2]; v[2] = v[3]; v[3] = t;   // CNOT: swap |10> <-> |11>
    }
}

// ---------------- Kernel B: per-channel block -> BN affine + Fourier coeffs ----------------
// ws_ch layout per channel o (stride 32 floats):
//   [0..2] = A,B,C for x0 ; [3..5] = A,B,C for x1 ; [6] = K0
//   [5+2f, 6+2f] = P_f, Q_f for canonical freqs f=1..12 (FM13/FN13)
__global__ __launch_bounds__(64) void qf_coeffs(const float* __restrict__ part,
                                                const float* __restrict__ F,
                                                const float* __restrict__ qparam,
                                                const float* __restrict__ g,
                                                const float* __restrict__ bb,
                                                float* __restrict__ ws_ch) {
    int o = blockIdx.x;
    int lane = threadIdx.x;

    // ---- stats: all lanes end up with the 5 totals (redundant, L2-resident) ----
    float s[5] = {0,0,0,0,0};
    for (int b = lane; b < 256; b += 64) {
        #pragma unroll
        for (int k = 0; k < 5; k++) s[k] += part[b * 5 + k];
    }
    #pragma unroll
    for (int k = 0; k < 5; k++) {
        #pragma unroll
        for (int off = 32; off; off >>= 1) s[k] += __shfl_xor(s[k], off, 64);
    }

    __shared__ cplx cols[9][4];   // 0..3: A1 columns, 4..7: A2 columns, 8: psi0
    __shared__ float pq[4][25];

    // ---- phase 1: lanes 0..8 evolve one basis vector each ----
    if (lane < 9) {
        int lvl  = (lane < 4) ? 1 : ((lane < 8) ? 2 : 0);
        int kidx = (lane < 4) ? lane : ((lane < 8) ? lane - 4 : 0);
        cplx v[4] = {{0,0},{0,0},{0,0},{0,0}};
        v[kidx] = {1.f, 0.f};
        apply_level(v, qparam, lvl, o);
        #pragma unroll
        for (int r = 0; r < 4; r++) cols[lane][r] = v[r];
    }
    __syncthreads();

    // ---- phase 2: lanes 0..3 each handle output row r ----
    if (lane < 4) {
        int r = lane;
        cplx psi0c[4];
        #pragma unroll
        for (int l = 0; l < 4; l++) psi0c[l] = cols[8][l];
        cplx B1[4][4];                    // B1[k][l] = A1[k][l] * psi0[l]
        #pragma unroll
        for (int l = 0; l < 4; l++)
            #pragma unroll
            for (int k = 0; k < 4; k++) B1[k][l] = cmul(cols[l][k], psi0c[l]);
        cplx A2r[4];                      // A2[r][k]
        #pragma unroll
        for (int k = 0; k < 4; k++) A2r[k] = cols[4 + k][r];

        cplx W[9];
        #pragma unroll
        for (int q = 0; q < 9; q++) W[q] = {0.f, 0.f};
        #pragma unroll
        for (int k = 0; k < 4; k++)
            #pragma unroll
            for (int l = 0; l < 4; l++) {
                cplx G = cmul(A2r[k], B1[k][l]);
                int si = SIDX25[(TM4[k] + TM4[l] + 2) * 5 + (TN4[k] + TN4[l] + 2)];
                W[si] = cadd(W[si], G);
            }

        cplx Acc[9][9];
        #pragma unroll
        for (int i = 0; i < 9; i++)
            #pragma unroll
            for (int j = 0; j < 9; j++) Acc[i][j] = {0.f, 0.f};
        #pragma unroll
        for (int s1 = 0; s1 < 9; s1++)
            #pragma unroll
            for (int s2 = 0; s2 < 9; s2++) {
                int mi = SM9[s1] - SM9[s2] + 4;
                int ni = SN9[s1] - SN9[s2] + 4;
                cplx X = cmul(W[s1], cconj(W[s2]));
                Acc[mi][ni] = cadd(Acc[mi][ni], X);
            }

        float sr = (r < 2) ? 1.f : -1.f;
        pq[r][0] = sr * Acc[4][4].re;
        #pragma unroll
        for (int f = 1; f < 13; f++) {
            cplx e1 = Acc[FM13[f] + 4][FN13[f] + 4];
            cplx e2 = Acc[4 - FM13[f]][4 - FN13[f]];
            pq[r][2 * f - 1] = sr * (e1.re + e2.re);      // P partial
            pq[r][2 * f]     = -sr * (e1.im - e2.im);     // Q partial
        }
    }
    __syncthreads();

    // ---- BN affine for bn channels 2o, 2o+1 ----
    if (lane < 2) {
        int t = 2 * o + lane;
        const float Ninv = 1.0f / 65536.0f;
        float m0 = s[0] * Ninv, m1 = s[1] * Ninv;
        float F0 = F[t * 2 + 0], F1 = F[t * 2 + 1];
        float mean = F0 * m0 + F1 * m1;
        float ex2  = (F0 * F0 * s[2] + 2.f * F0 * F1 * s[4] + F1 * F1 * s[3]) * Ninv;
        float var  = ex2 - mean * mean;
        float scale = g[t] / sqrtf(var + EPS_);
        float* dst = ws_ch + o * 32 + lane * 3;
        dst[0] = F0 * scale;
        dst[1] = F1 * scale;
        dst[2] = bb[t] - mean * scale;
    }
    if (lane == 0) {
        float* co = ws_ch + o * 32;
        #pragma unroll
        for (int j = 0; j < 25; j++)
            co[6 + j] = pq[0][j] + pq[1][j] + pq[2][j] + pq[3][j];
    }
}

// ---------------- Kernel C: main per-pixel evaluation (Fourier form) ----------------
__device__ __forceinline__ float qf_ev(float c0, float c1, const float* __restrict__ C) {
    float x0 = fmaf(C[0], c0, fmaf(C[1], c1, C[2]));
    float x1 = fmaf(C[3], c0, fmaf(C[4], c1, C[5]));
    float a = 0.5f * (x0 + x1), b = 0.5f * (x0 - x1);
    float sa, ca, sb, cb;
    __sincosf(a, &sa, &ca);
    __sincosf(b, &sb, &cb);
    float cc = ca * cb, ss = sa * sb, sc = sa * cb, cs = ca * sb;
    float c11  = cc - ss,  s11  = sc + cs;                    // (1,1)
    float c1m1 = cc + ss,  s1m1 = sc - cs;                    // (1,-1)
    float c20 = fmaf(ca, ca, -sa * sa), s20 = 2.f * sa * ca;  // (2,0)
    float c02 = fmaf(cb, cb, -sb * sb), s02 = 2.f * sb * cb;  // (0,2)
    float pa = c20 * c02, pb = s20 * s02, pc = s20 * c02, pd = c20 * s02;
    float c22  = pa - pb, s22  = pc + pd;                     // (2,2)
    float c2m2 = pa + pb, s2m2 = pc - pd;                     // (2,-2)
    float c40 = fmaf(c20, c20, -s20 * s20), s40 = 2.f * s20 * c20;  // (4,0)
    float c04 = fmaf(c02, c02, -s02 * s02), s04 = 2.f * s02 * c02;  // (0,4)
    float c31  = fmaf(c20, c11, -s20 * s11),  s31  = fmaf(s20, c11,  c20 * s11);   // (3,1)
    float c3m1 = fmaf(c20, c1m1, -s20 * s1m1), s3m1 = fmaf(s20, c1m1, c20 * s1m1); // (3,-1)
    float c13  = fmaf(c02, c11, -s02 * s11),  s13  = fmaf(s02, c11,  c02 * s11);   // (1,3)
    float c1m3 = fmaf(c1m1, c02, s1m1 * s02), s1m3 = fmaf(s1m1, c02, -c1m1 * s02); // (1,-3)
    float ev = C[6];
    ev = fmaf(C[7],  c11,  ev); ev = fmaf(C[8],  s11,  ev);
    ev = fmaf(C[9],  c1m1, ev); ev = fmaf(C[10], s1m1, ev);
    ev = fmaf(C[11], c20,  ev); ev = fmaf(C[12], s20,  ev);
    ev = fmaf(C[13], c02,  ev); ev = fmaf(C[14], s02,  ev);
    ev = fmaf(C[15], c22,  ev); ev = fmaf(C[16], s22,  ev);
    ev = fmaf(C[17], c2m2, ev); ev = fmaf(C[18], s2m2, ev);
    ev = fmaf(C[19], c40,  ev); ev = fmaf(C[20], s40,  ev);
    ev = fmaf(C[21], c04,  ev); ev = fmaf(C[22], s04,  ev);
    ev = fmaf(C[23], c31,  ev); ev = fmaf(C[24], s31,  ev);
    ev = fmaf(C[25], c3m1, ev); ev = fmaf(C[26], s3m1, ev);
    ev = fmaf(C[27], c13,  ev); ev = fmaf(C[28], s13,  ev);
    ev = fmaf(C[29], c1m3, ev); ev = fmaf(C[30], s1m3, ev);
    return ev;
}

// 4 float4-groups (16 pixels) per thread; grid (16,128) = 2048 blocks = one
// co-resident round (8 blocks/CU at 256 thr, 56 VGPR). 16 stores/thread.
__global__ __launch_bounds__(256) void qf_main(const float4* __restrict__ coords4,
                                               const float* __restrict__ ch,
                                               float4* __restrict__ out4) {
    int t = threadIdx.x;
    int o = blockIdx.y;                         // uniform per block
    const float* __restrict__ C = ch + o * 32;
    size_t obase = (size_t)o * (HW / 4);
    const size_t plane4 = (size_t)OC * (HW / 4);
    int g0 = blockIdx.x * 1024 + t;             // block covers 1024 contiguous groups
    #pragma unroll
    for (int j = 0; j < 4; j++) {
        int p4 = g0 + j * 256;
        float4 c0v = coords4[p4];
        float4 c1v = coords4[(HW / 4) + p4];
        float4 r;
        r.x = qf_ev(c0v.x, c1v.x, C);
        r.y = qf_ev(c0v.y, c1v.y, C);
        r.z = qf_ev(c0v.z, c1v.z, C);
        r.w = qf_ev(c0v.w, c1v.w, C);
        size_t bi = obase + (size_t)p4;
        out4[bi] = r;
        out4[bi + plane4] = r;
        out4[bi + 2 * plane4] = r;
        out4[bi + 3 * plane4] = r;
    }
}

extern "C" void kernel_launch(void* const* d_in, const int* in_sizes, int n_in,
                              void* d_out, int out_size, void* d_ws, size_t ws_size,
                              hipStream_t stream) {
    const float* coords = (const float*)d_in[0];
    const float* F      = (const float*)d_in[1];
    const float* qparam = (const float*)d_in[2];
    const float* g      = (const float*)d_in[3];
    const float* bb     = (const float*)d_in[4];
    float* out = (float*)d_out;

    float* ws    = (float*)d_ws;
    float* part  = ws;              // 256*5 = 1280 floats
    float* ws_ch = ws + 2048;       // 128*32 = 4096 floats

    qf_stats_partial<<<dim3(256), dim3(256), 0, stream>>>(coords, part);
    qf_coeffs<<<dim3(OC), dim3(64), 0, stream>>>(part, F, qparam, g, bb, ws_ch);
    qf_main<<<dim3(HW / 4 / 1024, OC), dim3(256), 0, stream>>>((const float4*)coords, ws_ch, (float4*)out);
}